// Round 3
// baseline (264.249 us; speedup 1.0000x reference)
//
#include <hip/hip_runtime.h>

#define C_IN   672
#define C_OUT  128
#define HW     49
#define XELEMS (C_IN*HW)      // 32928
#define BK     96             // K-chunk (3 MFMA k-steps)
#define NCH    7              // 672/96
#define CHUNK  (BK*HW)        // 4704 floats per chunk
#define NLD    19             // ceil(4704/256) scalar loads per thread per chunk
#define RS     100            // hT row stride in halfs (200 B): scalar-write bank step 18 -> 4-way (~free, m136)
#define NROWS  64             // padded N (s) dimension

typedef short  short8  __attribute__((ext_vector_type(8)));
typedef short  short4v __attribute__((ext_vector_type(4)));
typedef float  f4      __attribute__((ext_vector_type(4)));

__device__ __forceinline__ unsigned short f2bf(float f) {
    unsigned u = __float_as_uint(f);
    u += 0x7fffu + ((u >> 16) & 1u);
    return (unsigned short)(u >> 16);
}

__global__ __launch_bounds__(256) void prep_kernel(
        const float* __restrict__ gamma,
        const float* __restrict__ beta,
        const float* __restrict__ rmean,
        const float* __restrict__ rvar,
        const float* __restrict__ W,
        unsigned short* __restrict__ Wbf,
        float* __restrict__ scale,
        float* __restrict__ shift) {
    int i = blockIdx.x * 256 + threadIdx.x;
    if (i < C_IN) {
        float inv = rsqrtf(rvar[i] + 1e-5f);
        float sc  = gamma[i] * inv;
        scale[i] = sc;
        shift[i] = beta[i] - rmean[i] * sc;
    }
    if (i < C_OUT * C_IN) Wbf[i] = f2bf(W[i]);
}

// One block per batch element b: out_b(128x49) = W(128x672) @ h_b(672x49)
// h_b = relu(x_b * scale + shift), staged transposed (hT[s][c]) in LDS as bf16.
// R1-proven barrier protocol (load+write in one phase); scalar f32 loads so
// inter-lane LDS write stride = RS halfs (4-way bank alias only).
// No cross-iteration register pipeline, no min-waves launch bound (R2's
// timing-sensitive failure involved exactly those two).
__global__ __launch_bounds__(256) void gemm_kernel(
        const float* __restrict__ x,
        const unsigned short* __restrict__ Wbf,
        const float* __restrict__ scale,
        const float* __restrict__ shift,
        float* __restrict__ out) {
    __shared__ float s_scale[C_IN];
    __shared__ float s_shift[C_IN];
    __shared__ unsigned short hT[NROWS * RS];   // 12800 B

    const int tid  = threadIdx.x;
    const int b    = blockIdx.x;
    const int wv   = tid >> 6;        // wave 0..3 -> m-strip of 32 rows
    const int lane = tid & 63;
    const int quad = lane >> 4;
    const int l16  = lane & 15;

    const float* xb = x + (size_t)b * XELEMS;

    // zero hT once: pad rows 49..63 stay clean zeros for all chunks
    {
        unsigned long long* z = (unsigned long long*)hT;
        for (int i = tid; i < (NROWS * RS) / 4; i += 256) z[i] = 0ull;
    }
    for (int i = tid; i < C_IN; i += 256) {
        s_scale[i] = scale[i];
        s_shift[i] = shift[i];
    }

    f4 acc[2][4];
    #pragma unroll
    for (int mt = 0; mt < 2; ++mt)
        #pragma unroll
        for (int nt = 0; nt < 4; ++nt)
            acc[mt][nt] = (f4){0.f, 0.f, 0.f, 0.f};

    for (int ch = 0; ch < NCH; ++ch) {
        __syncthreads();   // prev MFMA done reading hT (also covers zero-fill + s_scale on ch==0)

        // ---- stage chunk: scalar loads (compiler batches all 19 per thread),
        // BN+ReLU+cvt, scalar u16 writes with lane stride = 1 spatial row
        const float* xc = xb + ch * CHUNK;
        #pragma unroll
        for (int i = 0; i < NLD; ++i) {
            int idx = i * 256 + tid;
            if (idx < CHUNK) {
                float raw = xc[idx];
                int c = idx / HW;               // magic-div by 49
                int s = idx - c * HW;
                int cg = ch * BK + c;
                float v = fmaxf(raw * s_scale[cg] + s_shift[cg], 0.f);
                hT[s * RS + c] = f2bf(v);
            }
        }
        __syncthreads();

        // ---- 3 MFMA k-steps over this chunk
        #pragma unroll
        for (int ks = 0; ks < 3; ++ks) {
            const int kloc = ks * 32 + quad * 8;
            short8 av[2];
            #pragma unroll
            for (int mt = 0; mt < 2; ++mt) {
                int row = wv * 32 + mt * 16 + l16;   // A from L2-resident bf16 W
                av[mt] = *(const short8*)(Wbf + row * C_IN + ch * BK + kloc);
            }
            short8 bv[4];
            #pragma unroll
            for (int nt = 0; nt < 4; ++nt) {
                int srow = nt * 16 + l16;            // B via two ds_read_b64
                const unsigned short* p = hT + srow * RS + kloc;
                short4v lo = *(const short4v*)(p);
                short4v hi = *(const short4v*)(p + 4);
                bv[nt] = __builtin_shufflevector(lo, hi, 0, 1, 2, 3, 4, 5, 6, 7);
            }
            #pragma unroll
            for (int mt = 0; mt < 2; ++mt)
                #pragma unroll
                for (int nt = 0; nt < 4; ++nt)
                    acc[mt][nt] = __builtin_amdgcn_mfma_f32_16x16x32_bf16(
                        av[mt], bv[nt], acc[mt][nt], 0, 0, 0);
        }
    }

    // ---- epilogue: C/D layout col=lane&15, row=quad*4+reg (m89-verified); mask s>=49
    float* outb = out + (size_t)b * (C_OUT * HW);
    #pragma unroll
    for (int mt = 0; mt < 2; ++mt) {
        #pragma unroll
        for (int nt = 0; nt < 4; ++nt) {
            int scol = nt * 16 + l16;
            if (scol < HW) {
                #pragma unroll
                for (int i = 0; i < 4; ++i) {
                    int o = wv * 32 + mt * 16 + quad * 4 + i;
                    outb[o * HW + scol] = acc[mt][nt][i];
                }
            }
        }
    }
}

extern "C" void kernel_launch(void* const* d_in, const int* in_sizes, int n_in,
                              void* d_out, int out_size, void* d_ws, size_t ws_size,
                              hipStream_t stream) {
    const float* x     = (const float*)d_in[0];
    const float* gamma = (const float*)d_in[1];
    const float* beta  = (const float*)d_in[2];
    const float* rmean = (const float*)d_in[3];
    const float* rvar  = (const float*)d_in[4];
    const float* W     = (const float*)d_in[5];
    float* out = (float*)d_out;

    // ws layout: [bf16 W: 86016*2 B][scale: 672 f32][shift: 672 f32]  (~173 KB)
    unsigned short* Wbf = (unsigned short*)d_ws;
    float* scale = (float*)((char*)d_ws + (size_t)C_OUT * C_IN * 2);
    float* shift = scale + C_IN;

    prep_kernel<<<(C_OUT * C_IN + 255) / 256, 256, 0, stream>>>(
        gamma, beta, rmean, rvar, W, Wbf, scale, shift);
    gemm_kernel<<<1024, 256, 0, stream>>>(x, Wbf, scale, shift, out);
}

// Round 4
// 221.788 us; speedup vs baseline: 1.1914x; 1.1914x over previous
//
#include <hip/hip_runtime.h>

#define C_IN   672
#define C_OUT  128
#define HW     49
#define XELEMS (C_IN*HW)      // 32928
#define BK     96             // K-chunk (3 MFMA k-steps)
#define NCH    7              // 672/96
#define CHUNK  (BK*HW)        // 4704 floats per chunk
#define NLD    19             // ceil(4704/256) scalar loads per thread per chunk
#define RS     100            // hT row stride in halfs (200 B): write bank step 18 -> 4-way (~free, m136)
#define NROWS  64             // padded N (s) dimension

typedef short  short8  __attribute__((ext_vector_type(8)));
typedef short  short4v __attribute__((ext_vector_type(4)));
typedef float  f4      __attribute__((ext_vector_type(4)));

__device__ __forceinline__ unsigned short f2bf(float f) {
    unsigned u = __float_as_uint(f);
    u += 0x7fffu + ((u >> 16) & 1u);
    return (unsigned short)(u >> 16);
}

__global__ __launch_bounds__(256) void prep_kernel(
        const float* __restrict__ gamma,
        const float* __restrict__ beta,
        const float* __restrict__ rmean,
        const float* __restrict__ rvar,
        const float* __restrict__ W,
        unsigned short* __restrict__ Wbf,
        float* __restrict__ scale,
        float* __restrict__ shift) {
    int i = blockIdx.x * 256 + threadIdx.x;
    if (i < C_IN) {
        float inv = rsqrtf(rvar[i] + 1e-5f);
        float sc  = gamma[i] * inv;
        scale[i] = sc;
        shift[i] = beta[i] - rmean[i] * sc;
    }
    if (i < C_OUT * C_IN) Wbf[i] = f2bf(W[i]);
}

// One block per batch element b: out_b(128x49) = W(128x672) @ h_b(672x49)
// h_b = relu(x_b * scale + shift), staged transposed (hT[s][c]) in LDS as bf16.
// R4: staging loads are BRANCH-FREE (clamped index) and issued in one batch
// before the barrier -> 19 loads in flight per wave instead of ~1 (R3 was
// latency-serialized: 116 us at 10% HBM BW). A-frags for the chunk prefetched
// in the same batch. Same 2-barrier protocol as the R1/R3-proven skeleton.
__global__ __launch_bounds__(256) void gemm_kernel(
        const float* __restrict__ x,
        const unsigned short* __restrict__ Wbf,
        const float* __restrict__ scale,
        const float* __restrict__ shift,
        float* __restrict__ out) {
    __shared__ float s_scale[C_IN];
    __shared__ float s_shift[C_IN];
    __shared__ unsigned short hT[NROWS * RS];   // 12800 B

    const int tid  = threadIdx.x;
    const int b    = blockIdx.x;
    const int wv   = tid >> 6;        // wave 0..3 -> m-strip of 32 rows
    const int lane = tid & 63;
    const int quad = lane >> 4;
    const int l16  = lane & 15;

    const float* xb = x + (size_t)b * XELEMS;

    // zero hT once: pad rows 49..63 stay clean zeros for all chunks
    {
        unsigned long long* z = (unsigned long long*)hT;
        for (int i = tid; i < (NROWS * RS) / 4; i += 256) z[i] = 0ull;
    }
    for (int i = tid; i < C_IN; i += 256) {
        s_scale[i] = scale[i];
        s_shift[i] = shift[i];
    }

    f4 acc[2][4];
    #pragma unroll
    for (int mt = 0; mt < 2; ++mt)
        #pragma unroll
        for (int nt = 0; nt < 4; ++nt)
            acc[mt][nt] = (f4){0.f, 0.f, 0.f, 0.f};

    for (int ch = 0; ch < NCH; ++ch) {
        // ---- batched load phase (branch-free: all 19 loads in flight at once)
        const float* xc = xb + ch * CHUNK;
        float r[NLD];
        #pragma unroll
        for (int i = 0; i < NLD; ++i) {
            int idx = i * 256 + tid;
            r[i] = xc[(idx < CHUNK) ? idx : 0];   // clamp, no branch
        }
        // ---- A-frag prefetch for this chunk (L2-resident bf16 W), same batch
        short8 av[3][2];
        #pragma unroll
        for (int ks = 0; ks < 3; ++ks)
            #pragma unroll
            for (int mt = 0; mt < 2; ++mt) {
                int row = wv * 32 + mt * 16 + l16;
                av[ks][mt] = *(const short8*)(Wbf + row * C_IN + ch * BK + ks * 32 + quad * 8);
            }

        __syncthreads();   // prev MFMA done reading hT (also drains our loads)

        // ---- write phase: BN+ReLU+cvt, scalar u16 writes, lane stride = 1 row
        #pragma unroll
        for (int i = 0; i < NLD; ++i) {
            int idx = i * 256 + tid;
            if (idx < CHUNK) {
                int c = idx / HW;               // magic-div by 49
                int s = idx - c * HW;
                int cg = ch * BK + c;
                float v = fmaxf(r[i] * s_scale[cg] + s_shift[cg], 0.f);
                hT[s * RS + c] = f2bf(v);
            }
        }
        __syncthreads();

        // ---- 3 MFMA k-steps over this chunk (A already in registers)
        #pragma unroll
        for (int ks = 0; ks < 3; ++ks) {
            const int kloc = ks * 32 + quad * 8;
            short8 bv[4];
            #pragma unroll
            for (int nt = 0; nt < 4; ++nt) {
                int srow = nt * 16 + l16;            // B via two ds_read_b64
                const unsigned short* p = hT + srow * RS + kloc;
                short4v lo = *(const short4v*)(p);
                short4v hi = *(const short4v*)(p + 4);
                bv[nt] = __builtin_shufflevector(lo, hi, 0, 1, 2, 3, 4, 5, 6, 7);
            }
            #pragma unroll
            for (int mt = 0; mt < 2; ++mt)
                #pragma unroll
                for (int nt = 0; nt < 4; ++nt)
                    acc[mt][nt] = __builtin_amdgcn_mfma_f32_16x16x32_bf16(
                        av[ks][mt], bv[nt], acc[mt][nt], 0, 0, 0);
        }
    }

    // ---- epilogue: C/D layout col=lane&15, row=quad*4+reg (m89-verified); mask s>=49
    float* outb = out + (size_t)b * (C_OUT * HW);
    #pragma unroll
    for (int mt = 0; mt < 2; ++mt) {
        #pragma unroll
        for (int nt = 0; nt < 4; ++nt) {
            int scol = nt * 16 + l16;
            if (scol < HW) {
                #pragma unroll
                for (int i = 0; i < 4; ++i) {
                    int o = wv * 32 + mt * 16 + quad * 4 + i;
                    outb[o * HW + scol] = acc[mt][nt][i];
                }
            }
        }
    }
}

extern "C" void kernel_launch(void* const* d_in, const int* in_sizes, int n_in,
                              void* d_out, int out_size, void* d_ws, size_t ws_size,
                              hipStream_t stream) {
    const float* x     = (const float*)d_in[0];
    const float* gamma = (const float*)d_in[1];
    const float* beta  = (const float*)d_in[2];
    const float* rmean = (const float*)d_in[3];
    const float* rvar  = (const float*)d_in[4];
    const float* W     = (const float*)d_in[5];
    float* out = (float*)d_out;

    // ws layout: [bf16 W: 86016*2 B][scale: 672 f32][shift: 672 f32]  (~173 KB)
    unsigned short* Wbf = (unsigned short*)d_ws;
    float* scale = (float*)((char*)d_ws + (size_t)C_OUT * C_IN * 2);
    float* shift = scale + C_IN;

    prep_kernel<<<(C_OUT * C_IN + 255) / 256, 256, 0, stream>>>(
        gamma, beta, rmean, rvar, W, Wbf, scale, shift);
    gemm_kernel<<<1024, 256, 0, stream>>>(x, Wbf, scale, shift, out);
}

// Round 5
// 218.494 us; speedup vs baseline: 1.2094x; 1.0151x over previous
//
#include <hip/hip_runtime.h>

#define C_IN   672
#define C_OUT  128
#define HW     49
#define XELEMS (C_IN*HW)      // 32928
#define BK     96             // K-chunk (3 MFMA k-steps)
#define NCH    7              // 672/96
#define CHUNK  (BK*HW)        // 4704 floats per chunk
#define NLD    19             // ceil(4704/256) transform iterations
#define NDMA   19             // ceil(18816 B / 1024 B) global_load_lds issues per chunk
#define RAWSZ  4864           // 18*256 + 64*4 floats (clamped tail lands in [4704,4864))
#define RS     100            // hT row stride in halfs (200 B): write bank step 18 -> 4-way (~free, m136)
#define NROWS  64             // padded N (s) dimension

typedef short  short8  __attribute__((ext_vector_type(8)));
typedef short  short4v __attribute__((ext_vector_type(4)));
typedef float  f4      __attribute__((ext_vector_type(4)));

__device__ __forceinline__ unsigned short f2bf(float f) {
    unsigned u = __float_as_uint(f);
    u += 0x7fffu + ((u >> 16) & 1u);
    return (unsigned short)(u >> 16);
}

__global__ __launch_bounds__(256) void prep_kernel(
        const float* __restrict__ gamma,
        const float* __restrict__ beta,
        const float* __restrict__ rmean,
        const float* __restrict__ rvar,
        const float* __restrict__ W,
        unsigned short* __restrict__ Wbf,
        float* __restrict__ scale,
        float* __restrict__ shift) {
    int i = blockIdx.x * 256 + threadIdx.x;
    if (i < C_IN) {
        float inv = rsqrtf(rvar[i] + 1e-5f);
        float sc  = gamma[i] * inv;
        scale[i] = sc;
        shift[i] = beta[i] - rmean[i] * sc;
    }
    if (i < C_OUT * C_IN) Wbf[i] = f2bf(W[i]);
}

// out_b(128x49) = W(128x672) @ relu(x_b*scale+shift)(672x49), one block per b.
// R5: x staged via global_load_lds DMA (fire-and-forget) issued AFTER syncB so
// the next chunk's loads are outstanding across the whole MFMA phase (drained
// at the next syncA). Chunk order rotated by b%7 to desynchronize the
// chip-wide fetch convoy (R1/R4 plateaued at ~74 us / 1.9 TB/s: phase-locked
// bursts + vmcnt(0) drains). Deterministic: per-block chunk order fixed by b.
__global__ __launch_bounds__(256) void gemm_kernel(
        const float* __restrict__ x,
        const unsigned short* __restrict__ Wbf,
        const float* __restrict__ scale,
        const float* __restrict__ shift,
        float* __restrict__ out) {
    __shared__ float s_scale[C_IN];
    __shared__ float s_shift[C_IN];
    __shared__ __align__(16) float raw[RAWSZ];        // 19456 B, DMA landing zone
    __shared__ unsigned short hT[NROWS * RS];          // 12800 B

    const int tid  = threadIdx.x;
    const int b    = blockIdx.x;
    const int wv   = tid >> 6;
    const int lane = tid & 63;
    const int quad = lane >> 4;
    const int l16  = lane & 15;

    const float* xb = x + (size_t)b * XELEMS;

    // zero hT once: pad rows 49..63 stay clean zeros for all chunks
    {
        unsigned long long* z = (unsigned long long*)hT;
        for (int i = tid; i < (NROWS * RS) / 4; i += 256) z[i] = 0ull;
    }
    for (int i = tid; i < C_IN; i += 256) {
        s_scale[i] = scale[i];
        s_shift[i] = shift[i];
    }

    // DMA one chunk of x into raw[]: 19 wave-level issues, 16 B/lane.
    // LDS dest = wave-uniform base + lane*16 (m104); per-lane gptr clamped so
    // the tail issue never reads past the chunk (stays in-bounds for b=1023).
    auto dma_chunk = [&](const float* xsrc) {
        for (int i = wv; i < NDMA; i += 4) {
            int fidx = i * 256 + lane * 4;
            if (fidx > CHUNK - 4) fidx = CHUNK - 4;
            __builtin_amdgcn_global_load_lds(
                (const __attribute__((address_space(1))) unsigned int*)(xsrc + fidx),
                (__attribute__((address_space(3))) unsigned int*)(raw + i * 256),
                16, 0, 0);
        }
    };

    f4 acc[2][4];
    #pragma unroll
    for (int mt = 0; mt < 2; ++mt)
        #pragma unroll
        for (int nt = 0; nt < 4; ++nt)
            acc[mt][nt] = (f4){0.f, 0.f, 0.f, 0.f};

    int kc = b % NCH;                 // rotated chunk order (fixed per block)
    dma_chunk(xb + kc * CHUNK);       // prologue DMA, drained by first syncA

    for (int it = 0; it < NCH; ++it) {
        __syncthreads();   // drains DMA(kc) + covers zero-fill/scales on it==0

        // A-frags for this chunk (L2-resident bf16 W); complete by syncB
        short8 av[3][2];
        #pragma unroll
        for (int ks = 0; ks < 3; ++ks)
            #pragma unroll
            for (int mt = 0; mt < 2; ++mt) {
                int row = wv * 32 + mt * 16 + l16;
                av[ks][mt] = *(const short8*)(Wbf + row * C_IN + kc * BK + ks * 32 + quad * 8);
            }

        // transform: LDS raw -> BN+ReLU+bf16 -> hT (scalar reads conflict-free,
        // writes 4-way aliased ~free)
        #pragma unroll
        for (int i = 0; i < NLD; ++i) {
            int idx = i * 256 + tid;
            if (idx < CHUNK) {
                float rv = raw[idx];
                int c = idx / HW;               // magic-div by 49
                int s = idx - c * HW;
                int cg = kc * BK + c;
                float v = fmaxf(rv * s_scale[cg] + s_shift[cg], 0.f);
                hT[s * RS + c] = f2bf(v);
            }
        }
        __syncthreads();   // hT ready; all transform reads of raw done

        // fire-and-forget DMA of the NEXT chunk: outstanding across MFMA phase
        int kn = kc + 1; if (kn == NCH) kn = 0;
        if (it + 1 < NCH) dma_chunk(xb + kn * CHUNK);

        // 3 MFMA k-steps on hT(kc)
        #pragma unroll
        for (int ks = 0; ks < 3; ++ks) {
            const int kloc = ks * 32 + quad * 8;
            short8 bv[4];
            #pragma unroll
            for (int nt = 0; nt < 4; ++nt) {
                int srow = nt * 16 + l16;            // two ds_read_b64
                const unsigned short* p = hT + srow * RS + kloc;
                short4v lo = *(const short4v*)(p);
                short4v hi = *(const short4v*)(p + 4);
                bv[nt] = __builtin_shufflevector(lo, hi, 0, 1, 2, 3, 4, 5, 6, 7);
            }
            #pragma unroll
            for (int mt = 0; mt < 2; ++mt)
                #pragma unroll
                for (int nt = 0; nt < 4; ++nt)
                    acc[mt][nt] = __builtin_amdgcn_mfma_f32_16x16x32_bf16(
                        av[ks][mt], bv[nt], acc[mt][nt], 0, 0, 0);
        }
        kc = kn;
    }

    // epilogue: C/D layout col=lane&15, row=quad*4+reg (m89-verified); mask s>=49
    float* outb = out + (size_t)b * (C_OUT * HW);
    #pragma unroll
    for (int mt = 0; mt < 2; ++mt) {
        #pragma unroll
        for (int nt = 0; nt < 4; ++nt) {
            int scol = nt * 16 + l16;
            if (scol < HW) {
                #pragma unroll
                for (int i = 0; i < 4; ++i) {
                    int o = wv * 32 + mt * 16 + quad * 4 + i;
                    outb[o * HW + scol] = acc[mt][nt][i];
                }
            }
        }
    }
}

extern "C" void kernel_launch(void* const* d_in, const int* in_sizes, int n_in,
                              void* d_out, int out_size, void* d_ws, size_t ws_size,
                              hipStream_t stream) {
    const float* x     = (const float*)d_in[0];
    const float* gamma = (const float*)d_in[1];
    const float* beta  = (const float*)d_in[2];
    const float* rmean = (const float*)d_in[3];
    const float* rvar  = (const float*)d_in[4];
    const float* W     = (const float*)d_in[5];
    float* out = (float*)d_out;

    // ws layout: [bf16 W: 86016*2 B][scale: 672 f32][shift: 672 f32]  (~173 KB)
    unsigned short* Wbf = (unsigned short*)d_ws;
    float* scale = (float*)((char*)d_ws + (size_t)C_OUT * C_IN * 2);
    float* shift = scale + C_IN;

    prep_kernel<<<(C_OUT * C_IN + 255) / 256, 256, 0, stream>>>(
        gamma, beta, rmean, rvar, W, Wbf, scale, shift);
    gemm_kernel<<<1024, 256, 0, stream>>>(x, Wbf, scale, shift, out);
}